// Round 1
// baseline (27056.067 us; speedup 1.0000x reference)
//
#include <hip/hip_runtime.h>

// 2-layer LSTM, B=64, S=2048, F=40, EMB=128, HID=256.
// Persistent flag-synced design:
//   4 batch-groups x 16 batches. Per group, per layer, NJ=8 blocks each owning a
//   32-wide h-slice (=128 gate rows) with bf16 MFMA B-fragments held in VGPRs.
//   h exchanged per step via agent-scope atomics in ws; layers pipelined (PIPE=4 ring).
//   In-projection folded (W_comb = W_ih0 @ W_in) and fused into the step loop.
//   Numerics: weights bf16, A-operands hi/lo bf16 split, c/h/gates fp32.

#define Sz    2048
#define PIPE  4
#define NG    4
#define NJ    8

typedef __attribute__((ext_vector_type(8))) short short8;
typedef __attribute__((ext_vector_type(4))) float f32x4;

// workspace word offsets
#define PUB0_OFF 0
#define PUB1_OFF 65536
#define FLG0_OFF 131072
#define FLG1_OFF (131072 + 128)
#define WS_WORDS (131072 + 256)

// LDS byte offsets
#define HA_HI 0
#define HA_LO 8448
#define HB_HI 16896
#define HB_LO 25344
#define IN_HI 33792
#define IN_LO 36096
#define GBUF  38400
#define SMEM_BYTES 46848
#define WCOMB_OFF 16896   // aliases HB+IN region, used only pre-loop by layer 0

__device__ __forceinline__ unsigned short bf16_rne(float f) {
  unsigned u = __float_as_uint(f);
  u += 0x7FFFu + ((u >> 16) & 1u);
  return (unsigned short)(u >> 16);
}
__device__ __forceinline__ float sigm(float x) { return 1.f / (1.f + __expf(-x)); }
__device__ __forceinline__ float tanh_f(float x) { return 1.f - 2.f / (__expf(2.f * x) + 1.f); }

__device__ __forceinline__ void stage_word(char* hi, char* lo, int e, int qs, unsigned wrd) {
  float f = __uint_as_float(wrd);
  unsigned short hb = bf16_rne(f);
  float fh = __uint_as_float((unsigned)hb << 16);
  unsigned short lb = bf16_rne(f - fh);
  int m = e >> 5, col = qs * 32 + (e & 31);
  *(short*)(hi + m * 528 + col * 2) = (short)hb;
  *(short*)(lo + m * 528 + col * 2) = (short)lb;
}

__device__ __forceinline__ void read_stage_stream(unsigned* src, char* hi, char* lo, int tid) {
  unsigned r0[8], r1[8];
#pragma unroll
  for (int qs = 0; qs < 8; ++qs) {
    r0[qs] = __hip_atomic_load(src + qs * 512 + tid,       __ATOMIC_RELAXED, __HIP_MEMORY_SCOPE_AGENT);
    r1[qs] = __hip_atomic_load(src + qs * 512 + 256 + tid, __ATOMIC_RELAXED, __HIP_MEMORY_SCOPE_AGENT);
  }
#pragma unroll
  for (int qs = 0; qs < 8; ++qs) {
    stage_word(hi, lo, tid,       qs, r0[qs]);
    stage_word(hi, lo, tid + 256, qs, r1[qs]);
  }
}

__global__ void zero_kernel(unsigned* __restrict__ ws, float* __restrict__ out) {
  int i = blockIdx.x * 256 + threadIdx.x;
  if (i < WS_WORDS) ws[i] = 0u;
  if (i < 64 * Sz) out[i] = 0.f;
}

__global__ __launch_bounds__(256, 1) void lstm_persist(
    const float* __restrict__ xin, const float* __restrict__ W_in,
    const float* __restrict__ b_in, const float* __restrict__ W_ih0,
    const float* __restrict__ W_hh0, const float* __restrict__ b_ih0,
    const float* __restrict__ b_hh0, const float* __restrict__ W_ih1,
    const float* __restrict__ W_hh1, const float* __restrict__ b_ih1,
    const float* __restrict__ b_hh1, const float* __restrict__ W_out,
    const float* __restrict__ b_out, float* __restrict__ out,
    unsigned* __restrict__ ws) {
  const int bx = blockIdx.x;
  const int g = bx & 7;          // group -> XCD class (L2 locality heuristic)
  if (g >= NG) return;
  const int idx = bx >> 3;       // 0..15
  const int layer = idx >> 3;    // 0 or 1
  const int p = idx & 7;         // j-split slice
  const int tid = (int)threadIdx.x;
  const int w = tid >> 6;        // wave = gate (i,f,g,o)
  const int lane = tid & 63;
  const int q = lane >> 4;
  const int n16 = lane & 15;

  __shared__ __align__(16) char smem[SMEM_BYTES];

  const int row0 = w * 256 + p * 32 + n16;   // absolute gate rows (u=0,1)
  const int row1 = row0 + 16;

  short8 wf_rec[8][2];   // W_hh frags [ktile][u]
  short8 wf_in2[8][2];   // layer1: W_ih1 frags
  short8 wf_cmb[2][2];   // layer0: W_comb frags (K padded 40->64)
  float bias0 = 0.f, bias1 = 0.f;

  // ---------------- startup: persistent weight fragments ----------------
  {
    const float* Wrec = layer ? W_hh1 : W_hh0;
#pragma unroll
    for (int kt = 0; kt < 8; ++kt) {
#pragma unroll
      for (int u = 0; u < 2; ++u) {
        const int row = u ? row1 : row0;
        const float* src = Wrec + (size_t)row * 256 + kt * 32 + q * 8;
        union { short8 v; unsigned short s[8]; } fr;
#pragma unroll
        for (int j = 0; j < 8; ++j) fr.s[j] = bf16_rne(src[j]);
        wf_rec[kt][u] = fr.v;
      }
    }
  }
  if (layer == 1) {
#pragma unroll
    for (int kt = 0; kt < 8; ++kt) {
#pragma unroll
      for (int u = 0; u < 2; ++u) {
        const int row = u ? row1 : row0;
        const float* src = W_ih1 + (size_t)row * 256 + kt * 32 + q * 8;
        union { short8 v; unsigned short s[8]; } fr;
#pragma unroll
        for (int j = 0; j < 8; ++j) fr.s[j] = bf16_rne(src[j]);
        wf_in2[kt][u] = fr.v;
      }
    }
    bias0 = b_ih1[row0] + b_hh1[row0];
    bias1 = b_ih1[row1] + b_hh1[row1];
  } else {
    // W_comb = W_ih0 @ W_in for this block's 128 gate rows, staged via LDS
    float* wcomb = (float*)(smem + WCOMB_OFF);
    for (int i = tid; i < 128 * 40; i += 256) {
      int rl = i / 40, f = i - rl * 40;
      int gate = rl >> 5, rr = rl & 31;
      int arow = gate * 256 + p * 32 + rr;
      const float* wi = W_ih0 + (size_t)arow * 128;
      float s = 0.f;
      for (int e = 0; e < 128; ++e) s += wi[e] * W_in[e * 40 + f];
      wcomb[rl * 40 + f] = s;
    }
    __syncthreads();
#pragma unroll
    for (int kt = 0; kt < 2; ++kt) {
#pragma unroll
      for (int u = 0; u < 2; ++u) {
        int rl = w * 32 + u * 16 + n16;
        union { short8 v; unsigned short s[8]; } fr;
#pragma unroll
        for (int j = 0; j < 8; ++j) {
          int k = kt * 32 + q * 8 + j;
          fr.s[j] = (k < 40) ? bf16_rne(wcomb[rl * 40 + k]) : (unsigned short)0;
        }
        wf_cmb[kt][u] = fr.v;
      }
    }
    {
      const float* wi0 = W_ih0 + (size_t)row0 * 128;
      const float* wi1 = W_ih0 + (size_t)row1 * 128;
      float s0 = 0.f, s1 = 0.f;
      for (int e = 0; e < 128; ++e) { s0 += wi0[e] * b_in[e]; s1 += wi1[e] * b_in[e]; }
      bias0 = s0 + b_ih0[row0] + b_hh0[row0];
      bias1 = s1 + b_ih0[row1] + b_hh0[row1];
    }
    __syncthreads();  // done with wcomb alias
    // zero input planes once (cols 40..63 stay zero forever)
    for (int i = tid; i < 2304; i += 256) *((short*)(smem + IN_HI) + i) = 0;
    __syncthreads();
  }

  float c0 = 0.f, c1 = 0.f;   // cell state, elements e=tid and e=tid+256
  float wo = 0.f, bo = 0.f;
  if (layer == 1) { wo = W_out[p * 32 + (tid & 31)]; bo = b_out[0]; }

  unsigned* const pubA  = ws + (layer ? PUB1_OFF : PUB0_OFF);
  unsigned* const flgMy = ws + (layer ? FLG1_OFF : FLG0_OFF) + g * 32 + p;
  float* gb = (float*)(smem + GBUF);

#pragma unroll 1
  for (int t = 0; t < Sz; ++t) {
    // prefetch input row (layer 0) before polling so latency overlaps
    float4 inv = make_float4(0.f, 0.f, 0.f, 0.f);
    int bb = 0, f4 = 0;
    if (layer == 0 && tid < 160) {
      bb = tid / 10; f4 = tid - bb * 10;
      inv = *(const float4*)(xin + ((size_t)(g * 16 + bb) * Sz + t) * 40 + f4 * 4);
    }

    // ---- poll flags (wave 0) ----
    if (w == 0) {
      unsigned tgt0, tgt1;
      if (layer == 0) { tgt0 = (unsigned)t; tgt1 = (t >= PIPE) ? (unsigned)(t - PIPE + 1) : 0u; }
      else            { tgt0 = (unsigned)(t + 1); tgt1 = (unsigned)t; }
      const int li = lane & 15;
      unsigned* fp = (li < 8) ? (ws + FLG0_OFF + g * 32 + li)
                              : (ws + FLG1_OFF + g * 32 + (li - 8));
      const unsigned tgt = (li < 8) ? tgt0 : tgt1;
      int spin = 0;
      for (;;) {
        unsigned v = __hip_atomic_load(fp, __ATOMIC_ACQUIRE, __HIP_MEMORY_SCOPE_AGENT);
        if (__all((int)(v >= tgt))) break;
        if (++spin > 48) __builtin_amdgcn_s_sleep(2);
      }
    }
    __syncthreads();  // A

    // ---- read + stage recurrent h(t-1) into HA planes ----
    const int slot_r = (t + PIPE - 1) % PIPE;
    read_stage_stream(pubA + (size_t)((g * PIPE + slot_r) * NJ) * 512,
                      smem + HA_HI, smem + HA_LO, tid);
    if (layer == 1) {
      const int slot_c = t % PIPE;  // h0(t) from layer 0
      read_stage_stream(ws + PUB0_OFF + (size_t)((g * PIPE + slot_c) * NJ) * 512,
                        smem + HB_HI, smem + HB_LO, tid);
    } else if (tid < 160) {
#pragma unroll
      for (int cc = 0; cc < 4; ++cc) {
        float f = ((const float*)&inv)[cc];
        unsigned short hb = bf16_rne(f);
        float fh = __uint_as_float((unsigned)hb << 16);
        unsigned short lb = bf16_rne(f - fh);
        int col = f4 * 4 + cc;
        *(short*)(smem + IN_HI + bb * 144 + col * 2) = (short)hb;
        *(short*)(smem + IN_LO + bb * 144 + col * 2) = (short)lb;
      }
    }
    __syncthreads();  // B

    // ---- MFMA: gates = hprev@Whh^T (+ input stream) ----
    f32x4 acc0 = {0.f, 0.f, 0.f, 0.f};
    f32x4 acc1 = {0.f, 0.f, 0.f, 0.f};
    const int arow = (lane & 15) * 528;
    const int kcol = q * 8;
#pragma unroll
    for (int kt = 0; kt < 8; ++kt) {
      short8 aH = *(const short8*)(smem + HA_HI + arow + (kt * 32 + kcol) * 2);
      short8 aL = *(const short8*)(smem + HA_LO + arow + (kt * 32 + kcol) * 2);
      acc0 = __builtin_amdgcn_mfma_f32_16x16x32_bf16(aH, wf_rec[kt][0], acc0, 0, 0, 0);
      acc0 = __builtin_amdgcn_mfma_f32_16x16x32_bf16(aL, wf_rec[kt][0], acc0, 0, 0, 0);
      acc1 = __builtin_amdgcn_mfma_f32_16x16x32_bf16(aH, wf_rec[kt][1], acc1, 0, 0, 0);
      acc1 = __builtin_amdgcn_mfma_f32_16x16x32_bf16(aL, wf_rec[kt][1], acc1, 0, 0, 0);
    }
    if (layer == 1) {
#pragma unroll
      for (int kt = 0; kt < 8; ++kt) {
        short8 aH = *(const short8*)(smem + HB_HI + arow + (kt * 32 + kcol) * 2);
        short8 aL = *(const short8*)(smem + HB_LO + arow + (kt * 32 + kcol) * 2);
        acc0 = __builtin_amdgcn_mfma_f32_16x16x32_bf16(aH, wf_in2[kt][0], acc0, 0, 0, 0);
        acc0 = __builtin_amdgcn_mfma_f32_16x16x32_bf16(aL, wf_in2[kt][0], acc0, 0, 0, 0);
        acc1 = __builtin_amdgcn_mfma_f32_16x16x32_bf16(aH, wf_in2[kt][1], acc1, 0, 0, 0);
        acc1 = __builtin_amdgcn_mfma_f32_16x16x32_bf16(aL, wf_in2[kt][1], acc1, 0, 0, 0);
      }
    } else {
      const int arow_in = (lane & 15) * 144;
#pragma unroll
      for (int kt = 0; kt < 2; ++kt) {
        short8 aH = *(const short8*)(smem + IN_HI + arow_in + (kt * 32 + kcol) * 2);
        short8 aL = *(const short8*)(smem + IN_LO + arow_in + (kt * 32 + kcol) * 2);
        acc0 = __builtin_amdgcn_mfma_f32_16x16x32_bf16(aH, wf_cmb[kt][0], acc0, 0, 0, 0);
        acc0 = __builtin_amdgcn_mfma_f32_16x16x32_bf16(aL, wf_cmb[kt][0], acc0, 0, 0, 0);
        acc1 = __builtin_amdgcn_mfma_f32_16x16x32_bf16(aH, wf_cmb[kt][1], acc1, 0, 0, 0);
        acc1 = __builtin_amdgcn_mfma_f32_16x16x32_bf16(aL, wf_cmb[kt][1], acc1, 0, 0, 0);
      }
    }

    // ---- epilogue: activation per gate-wave, share via LDS ----
#pragma unroll
    for (int u = 0; u < 2; ++u) {
      f32x4 a = u ? acc1 : acc0;
      float bs = u ? bias1 : bias0;
#pragma unroll
      for (int r = 0; r < 4; ++r) {
        float v = a[r] + bs;
        v = (w == 2) ? tanh_f(v) : sigm(v);
        gb[w * 528 + (q * 4 + r) * 33 + u * 16 + n16] = v;
      }
    }
    __syncthreads();  // C

    // ---- combine gates, update c/h, publish ----
    const int slot_w = t % PIPE;
    unsigned* dst = pubA + (size_t)((g * PIPE + slot_w) * NJ + p) * 512;
#pragma unroll
    for (int k = 0; k < 2; ++k) {
      int e = tid + k * 256;
      int m = e >> 5, nn = e & 31;
      float iv = gb[0 * 528 + m * 33 + nn];
      float fv = gb[1 * 528 + m * 33 + nn];
      float gv = gb[2 * 528 + m * 33 + nn];
      float ov = gb[3 * 528 + m * 33 + nn];
      float c = k ? c1 : c0;
      c = fv * c + iv * gv;
      float h = ov * tanh_f(c);
      if (k) c1 = c; else c0 = c;
      __hip_atomic_store(dst + e, __float_as_uint(h), __ATOMIC_RELAXED, __HIP_MEMORY_SCOPE_AGENT);
      if (layer == 1) {
        float val = h * wo;
#pragma unroll
        for (int off = 16; off; off >>= 1) val += __shfl_down(val, off, 32);
        if (nn == 0) {
          if (p == 0) val += bo;
          atomicAdd(out + (size_t)(g * 16 + m) * Sz + t, val);
        }
      }
    }
    __threadfence();
    __syncthreads();  // D
    if (tid == 0)
      __hip_atomic_store(flgMy, (unsigned)(t + 1), __ATOMIC_RELEASE, __HIP_MEMORY_SCOPE_AGENT);
  }
}

extern "C" void kernel_launch(void* const* d_in, const int* in_sizes, int n_in,
                              void* d_out, int out_size, void* d_ws, size_t ws_size,
                              hipStream_t stream) {
  const float* xin   = (const float*)d_in[0];
  const float* W_in  = (const float*)d_in[1];
  const float* b_in  = (const float*)d_in[2];
  const float* W_ih0 = (const float*)d_in[3];
  const float* W_hh0 = (const float*)d_in[4];
  const float* b_ih0 = (const float*)d_in[5];
  const float* b_hh0 = (const float*)d_in[6];
  const float* W_ih1 = (const float*)d_in[7];
  const float* W_hh1 = (const float*)d_in[8];
  const float* b_ih1 = (const float*)d_in[9];
  const float* b_hh1 = (const float*)d_in[10];
  const float* W_out = (const float*)d_in[11];
  const float* b_out = (const float*)d_in[12];
  float* out = (float*)d_out;
  unsigned* ws = (unsigned*)d_ws;

  zero_kernel<<<(WS_WORDS + 255) / 256, 256, 0, stream>>>(ws, out);
  lstm_persist<<<128, 256, 0, stream>>>(xin, W_in, b_in, W_ih0, W_hh0, b_ih0, b_hh0,
                                        W_ih1, W_hh1, b_ih1, b_hh1, W_out, b_out,
                                        out, ws);
}

// Round 2
// 7578.398 us; speedup vs baseline: 3.5702x; 3.5702x over previous
//
#include <hip/hip_runtime.h>

// 2-layer LSTM, B=64, S=2048, F=40, EMB=128, HID=256.
// Persistent design, R2: single-round-trip sync via tag-embedded u64 publishes.
//   4 batch-groups x 16 batches. Per group, per layer, NJ=8 blocks each owning a
//   32-wide h-slice (=128 gate rows) with bf16 MFMA B-fragments held in VGPRs.
//   h published as u64 {tag32, bf16hi<<16|bf16lo} RELAXED agent atomics (bypass
//   L1/L2 -> coherent at IF$); consumers poll the data itself + block vote.
//   No fences, no acquire/release (no buffer_wbl2 / buffer_inv storms).
//   Layers pipelined via PIPE=4 ring; layer1 posts a consumption counter so
//   layer0 never overwrites an unread slot.
//   Numerics: weights bf16, A-operands hi/lo bf16 split (producer-side), c/h/gates fp32.

#define Sz    2048
#define PIPE  4
#define NG    4
#define NJ    8

typedef __attribute__((ext_vector_type(8))) short short8;
typedef __attribute__((ext_vector_type(4))) float f32x4;

// workspace layout
#define PUB0_U64 0            // [g][slot][p][512] u64
#define PUB1_U64 65536
#define CFLG_U32 262144       // 32 u32: layer1 consumption counters [g*8+p]
#define WS_U32   262176

// LDS byte offsets
#define HA_HI 0
#define HA_LO 8448
#define HB_HI 16896
#define HB_LO 25344
#define IN_HI 33792
#define IN_LO 36096
#define GBUF  38400
#define SMEM_BYTES 46848
#define WCOMB_OFF 16896   // aliases HB+IN region, used only pre-loop by layer 0

__device__ __forceinline__ unsigned short bf16_rne(float f) {
  unsigned u = __float_as_uint(f);
  u += 0x7FFFu + ((u >> 16) & 1u);
  return (unsigned short)(u >> 16);
}
__device__ __forceinline__ float sigm(float x) { return 1.f / (1.f + __expf(-x)); }
__device__ __forceinline__ float tanh_f(float x) { return 1.f - 2.f / (__expf(2.f * x) + 1.f); }

// Load one slot's 8 slabs (4096 u64) across 256 threads, check embedded tags,
// stage bf16 hi/lo planes into LDS. Returns per-thread tag-ok predicate.
__device__ __forceinline__ bool load_stage(const unsigned long long* __restrict__ src,
                                           unsigned tagExp, char* hi, char* lo, int tid) {
  unsigned long long v[16];
#pragma unroll
  for (int kt = 0; kt < 8; ++kt) {
    v[kt * 2]     = __hip_atomic_load(src + kt * 512 + tid,       __ATOMIC_RELAXED, __HIP_MEMORY_SCOPE_AGENT);
    v[kt * 2 + 1] = __hip_atomic_load(src + kt * 512 + 256 + tid, __ATOMIC_RELAXED, __HIP_MEMORY_SCOPE_AGENT);
  }
  bool ok = true;
#pragma unroll
  for (int kt = 0; kt < 8; ++kt) {
#pragma unroll
    for (int hh = 0; hh < 2; ++hh) {
      unsigned long long x = v[kt * 2 + hh];
      ok &= ((unsigned)(x >> 32) == tagExp);
      unsigned pk = (unsigned)x;
      int e = tid + hh * 256;
      int m = e >> 5, col = kt * 32 + (e & 31);
      *(short*)(hi + m * 528 + col * 2) = (short)(pk >> 16);
      *(short*)(lo + m * 528 + col * 2) = (short)(pk & 0xffffu);
    }
  }
  return ok;
}

__global__ void zero_kernel(unsigned* __restrict__ ws, float* __restrict__ out) {
  int i = blockIdx.x * 256 + threadIdx.x;
  if (i < WS_U32) ws[i] = 0u;
  if (i < 64 * Sz) out[i] = 0.f;
}

__global__ __launch_bounds__(256, 1) void lstm_persist(
    const float* __restrict__ xin, const float* __restrict__ W_in,
    const float* __restrict__ b_in, const float* __restrict__ W_ih0,
    const float* __restrict__ W_hh0, const float* __restrict__ b_ih0,
    const float* __restrict__ b_hh0, const float* __restrict__ W_ih1,
    const float* __restrict__ W_hh1, const float* __restrict__ b_ih1,
    const float* __restrict__ b_hh1, const float* __restrict__ W_out,
    const float* __restrict__ b_out, float* __restrict__ out,
    unsigned* __restrict__ ws) {
  const int bx = blockIdx.x;
  const int g = bx & 7;          // group -> XCD class (locality heuristic only)
  if (g >= NG) return;
  const int idx = bx >> 3;       // 0..15
  const int layer = idx >> 3;    // 0 or 1
  const int p = idx & 7;         // j-split slice
  const int tid = (int)threadIdx.x;
  const int w = tid >> 6;        // wave = gate (i,f,g,o)
  const int lane = tid & 63;
  const int q = lane >> 4;
  const int n16 = lane & 15;

  __shared__ __align__(16) char smem[SMEM_BYTES];

  const int row0 = w * 256 + p * 32 + n16;   // absolute gate rows (u=0,1)
  const int row1 = row0 + 16;

  short8 wf_rec[8][2];   // W_hh frags [ktile][u]
  short8 wf_in2[8][2];   // layer1: W_ih1 frags
  short8 wf_cmb[2][2];   // layer0: W_comb frags (K padded 40->64)
  float bias0 = 0.f, bias1 = 0.f;

  // ---------------- startup: persistent weight fragments ----------------
  {
    const float* Wrec = layer ? W_hh1 : W_hh0;
#pragma unroll
    for (int kt = 0; kt < 8; ++kt) {
#pragma unroll
      for (int u = 0; u < 2; ++u) {
        const int row = u ? row1 : row0;
        const float* src = Wrec + (size_t)row * 256 + kt * 32 + q * 8;
        union { short8 v; unsigned short s[8]; } fr;
#pragma unroll
        for (int j = 0; j < 8; ++j) fr.s[j] = bf16_rne(src[j]);
        wf_rec[kt][u] = fr.v;
      }
    }
  }
  if (layer == 1) {
#pragma unroll
    for (int kt = 0; kt < 8; ++kt) {
#pragma unroll
      for (int u = 0; u < 2; ++u) {
        const int row = u ? row1 : row0;
        const float* src = W_ih1 + (size_t)row * 256 + kt * 32 + q * 8;
        union { short8 v; unsigned short s[8]; } fr;
#pragma unroll
        for (int j = 0; j < 8; ++j) fr.s[j] = bf16_rne(src[j]);
        wf_in2[kt][u] = fr.v;
      }
    }
    bias0 = b_ih1[row0] + b_hh1[row0];
    bias1 = b_ih1[row1] + b_hh1[row1];
  } else {
    // W_comb = W_ih0 @ W_in for this block's 128 gate rows, staged via LDS
    float* wcomb = (float*)(smem + WCOMB_OFF);
    for (int i = tid; i < 128 * 40; i += 256) {
      int rl = i / 40, f = i - rl * 40;
      int gate = rl >> 5, rr = rl & 31;
      int arow = gate * 256 + p * 32 + rr;
      const float* wi = W_ih0 + (size_t)arow * 128;
      float s = 0.f;
      for (int e = 0; e < 128; ++e) s += wi[e] * W_in[e * 40 + f];
      wcomb[rl * 40 + f] = s;
    }
    __syncthreads();
#pragma unroll
    for (int kt = 0; kt < 2; ++kt) {
#pragma unroll
      for (int u = 0; u < 2; ++u) {
        int rl = w * 32 + u * 16 + n16;
        union { short8 v; unsigned short s[8]; } fr;
#pragma unroll
        for (int j = 0; j < 8; ++j) {
          int k = kt * 32 + q * 8 + j;
          fr.s[j] = (k < 40) ? bf16_rne(wcomb[rl * 40 + k]) : (unsigned short)0;
        }
        wf_cmb[kt][u] = fr.v;
      }
    }
    {
      const float* wi0 = W_ih0 + (size_t)row0 * 128;
      const float* wi1 = W_ih0 + (size_t)row1 * 128;
      float s0 = 0.f, s1 = 0.f;
      for (int e = 0; e < 128; ++e) { s0 += wi0[e] * b_in[e]; s1 += wi1[e] * b_in[e]; }
      bias0 = s0 + b_ih0[row0] + b_hh0[row0];
      bias1 = s1 + b_ih0[row1] + b_hh0[row1];
    }
    __syncthreads();  // done with wcomb alias
    // zero input planes once (cols 40..63 stay zero forever)
    for (int i = tid; i < 2304; i += 256) *((short*)(smem + IN_HI) + i) = 0;
    __syncthreads();
  }

  float c0 = 0.f, c1 = 0.f;   // cell state, elements e=tid and e=tid+256
  float wo = 0.f, bo = 0.f;
  if (layer == 1) { wo = W_out[p * 32 + (tid & 31)]; bo = b_out[0]; }

  unsigned long long* const pub0 = (unsigned long long*)ws + PUB0_U64;
  unsigned long long* const pub1 = (unsigned long long*)ws + PUB1_U64;
  unsigned long long* const pubMy = layer ? pub1 : pub0;
  unsigned* const cflg = ws + CFLG_U32 + g * 8;
  float* gb = (float*)(smem + GBUF);

#pragma unroll 1
  for (int t = 0; t < Sz; ++t) {
    // ---- stage layer-0 input row for step t (local, no sync needed yet) ----
    if (layer == 0 && tid < 160) {
      int bb = tid / 10, f4 = tid - bb * 10;
      float4 inv = *(const float4*)(xin + ((size_t)(g * 16 + bb) * Sz + t) * 40 + f4 * 4);
#pragma unroll
      for (int cc = 0; cc < 4; ++cc) {
        float f = ((const float*)&inv)[cc];
        unsigned short hb = bf16_rne(f);
        float fh = __uint_as_float((unsigned)hb << 16);
        unsigned short lb = bf16_rne(f - fh);
        int col = f4 * 4 + cc;
        *(short*)(smem + IN_HI + bb * 144 + col * 2) = (short)hb;
        *(short*)(smem + IN_LO + bb * 144 + col * 2) = (short)lb;
      }
    }

    // ---- single-RT poll: read data+tags, stage to LDS, block vote ----
    const int slot_r = (t + PIPE - 1) % PIPE;                 // h(t-1) of own layer
    const unsigned long long* srcA = pubMy + (size_t)((g * PIPE + slot_r) * NJ) * 512;
    const unsigned long long* srcB = pub0 + (size_t)((g * PIPE + (t % PIPE)) * NJ) * 512; // h0(t)
    const unsigned tagA = (unsigned)t;        // h(t-1) carries tag t
    const unsigned tagB = (unsigned)(t + 1);  // h0(t) carries tag t+1
    for (;;) {
      bool ok = load_stage(srcA, tagA, smem + HA_HI, smem + HA_LO, tid);
      if (layer == 1) {
        ok &= load_stage(srcB, tagB, smem + HB_HI, smem + HB_LO, tid);
      } else if (tid < 8) {
        // anti-overwrite: layer1 must have consumed step (t-4) inputs
        unsigned c = __hip_atomic_load(cflg + tid, __ATOMIC_RELAXED, __HIP_MEMORY_SCOPE_AGENT);
        ok &= ((int)c >= t - 3);
      }
      if (__syncthreads_and(ok)) break;
    }
    if (layer == 1 && tid == 0)  // consumption counter (reads above are complete)
      __hip_atomic_store(cflg + p, (unsigned)(t + 1), __ATOMIC_RELAXED, __HIP_MEMORY_SCOPE_AGENT);

    // ---- MFMA: gates = hprev@Whh^T (+ input stream) ----
    f32x4 acc0 = {0.f, 0.f, 0.f, 0.f};
    f32x4 acc1 = {0.f, 0.f, 0.f, 0.f};
    const int arow = n16 * 528;
    const int kcol = q * 8;
#pragma unroll
    for (int kt = 0; kt < 8; ++kt) {
      short8 aH = *(const short8*)(smem + HA_HI + arow + (kt * 32 + kcol) * 2);
      short8 aL = *(const short8*)(smem + HA_LO + arow + (kt * 32 + kcol) * 2);
      acc0 = __builtin_amdgcn_mfma_f32_16x16x32_bf16(aH, wf_rec[kt][0], acc0, 0, 0, 0);
      acc0 = __builtin_amdgcn_mfma_f32_16x16x32_bf16(aL, wf_rec[kt][0], acc0, 0, 0, 0);
      acc1 = __builtin_amdgcn_mfma_f32_16x16x32_bf16(aH, wf_rec[kt][1], acc1, 0, 0, 0);
      acc1 = __builtin_amdgcn_mfma_f32_16x16x32_bf16(aL, wf_rec[kt][1], acc1, 0, 0, 0);
    }
    if (layer == 1) {
#pragma unroll
      for (int kt = 0; kt < 8; ++kt) {
        short8 aH = *(const short8*)(smem + HB_HI + arow + (kt * 32 + kcol) * 2);
        short8 aL = *(const short8*)(smem + HB_LO + arow + (kt * 32 + kcol) * 2);
        acc0 = __builtin_amdgcn_mfma_f32_16x16x32_bf16(aH, wf_in2[kt][0], acc0, 0, 0, 0);
        acc0 = __builtin_amdgcn_mfma_f32_16x16x32_bf16(aL, wf_in2[kt][0], acc0, 0, 0, 0);
        acc1 = __builtin_amdgcn_mfma_f32_16x16x32_bf16(aH, wf_in2[kt][1], acc1, 0, 0, 0);
        acc1 = __builtin_amdgcn_mfma_f32_16x16x32_bf16(aL, wf_in2[kt][1], acc1, 0, 0, 0);
      }
    } else {
      const int arow_in = n16 * 144;
#pragma unroll
      for (int kt = 0; kt < 2; ++kt) {
        short8 aH = *(const short8*)(smem + IN_HI + arow_in + (kt * 32 + kcol) * 2);
        short8 aL = *(const short8*)(smem + IN_LO + arow_in + (kt * 32 + kcol) * 2);
        acc0 = __builtin_amdgcn_mfma_f32_16x16x32_bf16(aH, wf_cmb[kt][0], acc0, 0, 0, 0);
        acc0 = __builtin_amdgcn_mfma_f32_16x16x32_bf16(aL, wf_cmb[kt][0], acc0, 0, 0, 0);
        acc1 = __builtin_amdgcn_mfma_f32_16x16x32_bf16(aH, wf_cmb[kt][1], acc1, 0, 0, 0);
        acc1 = __builtin_amdgcn_mfma_f32_16x16x32_bf16(aL, wf_cmb[kt][1], acc1, 0, 0, 0);
      }
    }

    // ---- epilogue: activation per gate-wave, share via LDS ----
#pragma unroll
    for (int u = 0; u < 2; ++u) {
      f32x4 a = u ? acc1 : acc0;
      float bs = u ? bias1 : bias0;
#pragma unroll
      for (int r = 0; r < 4; ++r) {
        float v = a[r] + bs;
        v = (w == 2) ? tanh_f(v) : sigm(v);
        gb[w * 528 + (q * 4 + r) * 33 + u * 16 + n16] = v;
      }
    }
    __syncthreads();

    // ---- combine gates, update c/h, publish {tag, bf16hi|bf16lo} ----
    unsigned long long* dst =
        pubMy + (size_t)((g * PIPE + (t % PIPE)) * NJ + p) * 512;
    const unsigned long long tagW = ((unsigned long long)(unsigned)(t + 1)) << 32;
#pragma unroll
    for (int k = 0; k < 2; ++k) {
      int e = tid + k * 256;
      int m = e >> 5, nn = e & 31;
      float iv = gb[0 * 528 + m * 33 + nn];
      float fv = gb[1 * 528 + m * 33 + nn];
      float gv = gb[2 * 528 + m * 33 + nn];
      float ov = gb[3 * 528 + m * 33 + nn];
      float c = k ? c1 : c0;
      c = fv * c + iv * gv;
      float h = ov * tanh_f(c);
      if (k) c1 = c; else c0 = c;
      unsigned short hb = bf16_rne(h);
      float fh = __uint_as_float((unsigned)hb << 16);
      unsigned short lb = bf16_rne(h - fh);
      unsigned pk = ((unsigned)hb << 16) | (unsigned)lb;
      __hip_atomic_store(dst + e, tagW | pk, __ATOMIC_RELAXED, __HIP_MEMORY_SCOPE_AGENT);
      if (layer == 1) {
        float val = h * wo;
#pragma unroll
        for (int off = 16; off; off >>= 1) val += __shfl_down(val, off, 32);
        if (nn == 0) {
          if (p == 0) val += bo;
          atomicAdd(out + (size_t)(g * 16 + m) * Sz + t, val);
        }
      }
    }
    // no fence, no flag: tags embedded in data; next step's vote barrier
    // provides the intra-block ordering we need.
  }
}

extern "C" void kernel_launch(void* const* d_in, const int* in_sizes, int n_in,
                              void* d_out, int out_size, void* d_ws, size_t ws_size,
                              hipStream_t stream) {
  const float* xin   = (const float*)d_in[0];
  const float* W_in  = (const float*)d_in[1];
  const float* b_in  = (const float*)d_in[2];
  const float* W_ih0 = (const float*)d_in[3];
  const float* W_hh0 = (const float*)d_in[4];
  const float* b_ih0 = (const float*)d_in[5];
  const float* b_hh0 = (const float*)d_in[6];
  const float* W_ih1 = (const float*)d_in[7];
  const float* W_hh1 = (const float*)d_in[8];
  const float* b_ih1 = (const float*)d_in[9];
  const float* b_hh1 = (const float*)d_in[10];
  const float* W_out = (const float*)d_in[11];
  const float* b_out = (const float*)d_in[12];
  float* out = (float*)d_out;
  unsigned* ws = (unsigned*)d_ws;

  zero_kernel<<<(WS_U32 + 255) / 256, 256, 0, stream>>>(ws, out);
  lstm_persist<<<128, 256, 0, stream>>>(xin, W_in, b_in, W_ih0, W_hh0, b_ih0, b_hh0,
                                        W_ih1, W_hh1, b_ih1, b_hh1, W_out, b_out,
                                        out, ws);
}